// Round 4
// baseline (26.199 us; speedup 1.0000x reference)
//
#include <hip/hip_runtime.h>

// CrossNet (DCN cross layers): B=16384, D=1024, L=3
//
// R3: algebraic restructure. xl_t = alpha_t * x0 + beta_t with scalar alpha
// and ROW-INDEPENDENT beta_t = sum_{u<t} b_u. Then:
//   d_t = x0 . w_t                  (3 independent dots per row)
//   c_1 = b0 . w1, c_2 = (b0+b1).w2 (row-independent, computed per wave)
//   alpha_0 = 1; s_t = alpha_t*d_t + c_t; alpha_{t+1} = alpha_t + s_t
//   out = alpha_3 * x0 + (b0+b1+b2)
// -> ONE interleaved 8-value butterfly per wave (no serial layer chain).
// 2 rows per wave, 64 lanes x 16 floats/row, no LDS, no barriers.

#define CN_B 16384
#define CN_D 1024
#define ROWS_PER_WAVE 2
#define WAVES_PER_BLOCK 4
#define ROWS_PER_BLOCK (ROWS_PER_WAVE * WAVES_PER_BLOCK)

__device__ __forceinline__ float dot4(const float4 a, const float4 b) {
  return a.x * b.x + a.y * b.y + a.z * b.z + a.w * b.w;
}

__global__ __launch_bounds__(256, 4) void crossnet_kernel(
    const float* __restrict__ x,
    const float* __restrict__ w,
    const float* __restrict__ bias,
    float* __restrict__ out) {
  const int tid  = threadIdx.x;
  const int wave = tid >> 6;
  const int lane = tid & 63;
  const int row0 = (blockIdx.x * WAVES_PER_BLOCK + wave) * ROWS_PER_WAVE;

  const float4* xr0 = reinterpret_cast<const float4*>(x + (size_t)row0 * CN_D);
  const float4* xr1 = reinterpret_cast<const float4*>(x + (size_t)(row0 + 1) * CN_D);
  const float4* w0r = reinterpret_cast<const float4*>(w);
  const float4* w1r = reinterpret_cast<const float4*>(w + CN_D);
  const float4* w2r = reinterpret_cast<const float4*>(w + 2 * CN_D);
  const float4* b0r = reinterpret_cast<const float4*>(bias);
  const float4* b1r = reinterpret_cast<const float4*>(bias + CN_D);
  const float4* b2r = reinterpret_cast<const float4*>(bias + 2 * CN_D);

  float4 x0a[4], x0b[4];
  #pragma unroll
  for (int k = 0; k < 4; ++k) {
    x0a[k] = xr0[k * 64 + lane];
    x0b[k] = xr1[k * 64 + lane];
  }

  // 8 independent partial reductions: d0..d2 for two rows, c1, c2
  float da0 = 0.f, da1 = 0.f, da2 = 0.f;
  float db0 = 0.f, db1 = 0.f, db2 = 0.f;
  float c1 = 0.f, c2 = 0.f;
  float4 bs[4];  // b0+b1+b2 fragment

  #pragma unroll
  for (int k = 0; k < 4; ++k) {
    const int idx = k * 64 + lane;
    const float4 w0 = w0r[idx];
    const float4 w1 = w1r[idx];
    const float4 w2 = w2r[idx];
    const float4 b0 = b0r[idx];
    const float4 b1 = b1r[idx];
    const float4 b2 = b2r[idx];

    da0 += dot4(x0a[k], w0);  db0 += dot4(x0b[k], w0);
    da1 += dot4(x0a[k], w1);  db1 += dot4(x0b[k], w1);
    da2 += dot4(x0a[k], w2);  db2 += dot4(x0b[k], w2);

    c1 += dot4(b0, w1);
    float4 b01;
    b01.x = b0.x + b1.x; b01.y = b0.y + b1.y;
    b01.z = b0.z + b1.z; b01.w = b0.w + b1.w;
    c2 += dot4(b01, w2);
    bs[k].x = b01.x + b2.x; bs[k].y = b01.y + b2.y;
    bs[k].z = b01.z + b2.z; bs[k].w = b01.w + b2.w;
  }

  // one interleaved 64-lane butterfly over all 8 values (ILP=8)
  #pragma unroll
  for (int off = 32; off > 0; off >>= 1) {
    da0 += __shfl_xor(da0, off, 64);
    da1 += __shfl_xor(da1, off, 64);
    da2 += __shfl_xor(da2, off, 64);
    db0 += __shfl_xor(db0, off, 64);
    db1 += __shfl_xor(db1, off, 64);
    db2 += __shfl_xor(db2, off, 64);
    c1  += __shfl_xor(c1,  off, 64);
    c2  += __shfl_xor(c2,  off, 64);
  }

  // scalar recurrence (3 fused steps per row)
  float aa = 1.0f + da0;                 // alpha_1 (s0 = d0, c0 = 0)
  aa = aa + (aa * da1 + c1);             // alpha_2
  aa = aa + (aa * da2 + c2);             // alpha_3
  float ab = 1.0f + db0;
  ab = ab + (ab * db1 + c1);
  ab = ab + (ab * db2 + c2);

  float4* or0 = reinterpret_cast<float4*>(out + (size_t)row0 * CN_D);
  float4* or1 = reinterpret_cast<float4*>(out + (size_t)(row0 + 1) * CN_D);
  #pragma unroll
  for (int k = 0; k < 4; ++k) {
    float4 oa, ob;
    oa.x = x0a[k].x * aa + bs[k].x;  ob.x = x0b[k].x * ab + bs[k].x;
    oa.y = x0a[k].y * aa + bs[k].y;  ob.y = x0b[k].y * ab + bs[k].y;
    oa.z = x0a[k].z * aa + bs[k].z;  ob.z = x0b[k].z * ab + bs[k].z;
    oa.w = x0a[k].w * aa + bs[k].w;  ob.w = x0b[k].w * ab + bs[k].w;
    or0[k * 64 + lane] = oa;
    or1[k * 64 + lane] = ob;
  }
}

extern "C" void kernel_launch(void* const* d_in, const int* in_sizes, int n_in,
                              void* d_out, int out_size, void* d_ws, size_t ws_size,
                              hipStream_t stream) {
  const float* x    = (const float*)d_in[0];
  const float* w    = (const float*)d_in[1];
  const float* bias = (const float*)d_in[2];
  float* out        = (float*)d_out;

  crossnet_kernel<<<CN_B / ROWS_PER_BLOCK, 256, 0, stream>>>(x, w, bias, out);
}